// Round 1
// baseline (945.550 us; speedup 1.0000x reference)
//
#include <hip/hip_runtime.h>

#define SEQ_LEN 4096
#define D_MODEL 512
#define KSZ 33

typedef __attribute__((ext_vector_type(4))) float float4v;
typedef __attribute__((ext_vector_type(8))) short short8;
typedef __attribute__((ext_vector_type(8))) unsigned short ushort8;

static __device__ __forceinline__ unsigned short f2bf(float f) {
    unsigned int u = __float_as_uint(f);
    u += 0x7fffu + ((u >> 16) & 1u);   // round-to-nearest-even
    return (unsigned short)(u >> 16);
}

// ---------------- K0: prep — backbone W fp32->bf16 (16384 elems into d_ws),
// conv weights transposed to wt[k][d] fp32 (33*512) so K1 reads them coalesced.
__global__ __launch_bounds__(256) void k_prep(const float* __restrict__ bw,
                                              const float* __restrict__ cw,
                                              unsigned short* __restrict__ wb,
                                              float* __restrict__ wt) {
    int i = blockIdx.x * 256 + threadIdx.x;
    if (i < 128 * 128) wb[i] = f2bf(bw[i]);
    if (i < KSZ * D_MODEL) {
        int k = i >> 9, d = i & 511;           // i = k*512 + d
        wt[i] = cw[(size_t)d * KSZ + k];
    }
}

// ---------------- K1: residual depthwise conv, fp32 compute -> bf16 out -----
// grid (64 l-tiles, 8 d-tiles, 32 b); block 256 (4 waves x 16 l-rows each).
// Writes bf16 hagg into the LOW 128 B of each 256 B (row, dtile) slot of out:
//   byte addr = (b*4096+l)*2048 + dt*256 + 2*d_local   (in-place, unique owner)
// Rolling 16-reg window: 48 LDS reads/thread total (vs compiler-sunk ~530).
__global__ __launch_bounds__(256, 6) void k_conv(const float* __restrict__ h,
                                                 const float* __restrict__ wt,
                                                 float* __restrict__ outp) {
    __shared__ float tile[96][64];   // 24576 B -> 6 blocks/CU; reused for out staging

    const int lt = blockIdx.x, dt = blockIdx.y, b = blockIdx.z;
    const int tid = threadIdx.x;
    const int l0 = lt * 64;

    // --- stage h tile with float4 (16 B/lane) ---
    const float* hb = h + ((size_t)b * SEQ_LEN) * D_MODEL + dt * 64;
    {
        const int cg = (tid & 15) * 4;
#pragma unroll
        for (int rr = 0; rr < 6; rr++) {
            int r = (tid >> 4) + rr * 16;
            int l = l0 - 16 + r;
            float4v v = {0.f, 0.f, 0.f, 0.f};
            if (l >= 0 && l < SEQ_LEN) v = *(const float4v*)(hb + (size_t)l * D_MODEL + cg);
            *(float4v*)(&tile[r][cg]) = v;
        }
    }
    __syncthreads();

    const int c = tid & 63;
    const int lsub = (tid >> 6) * 16;
    const float* wcol = wt + dt * 64 + c;      // wt[k][dt*64+c], L1-resident

    float buf[16];                              // rolling window: h[l0-16+lsub+k .. +k+15]
#pragma unroll
    for (int j = 0; j < 16; j++) buf[j] = tile[lsub + j][c];
    float acc[16] = {};
#pragma unroll
    for (int k = 0; k < KSZ; k++) {
        // residual h[l] == window value at k==16 -> fold into weight (+1)
        float wk = wcol[(size_t)k * D_MODEL] + ((k == 16) ? 1.0f : 0.0f);
#pragma unroll
        for (int j = 0; j < 16; j++) acc[j] += wk * buf[j];
        if (k < 32) {
#pragma unroll
            for (int j = 0; j < 15; j++) buf[j] = buf[j + 1];
            buf[15] = tile[lsub + k + 16][c];
        }
    }
    __syncthreads();   // all tile reads done before reuse

    // --- bf16 out staging in LDS, then 16 B/lane stores ---
    unsigned short* ot = (unsigned short*)&tile[0][0];   // [64 l][64 d] ushort = 8 KB
#pragma unroll
    for (int j = 0; j < 16; j++) ot[(lsub + j) * 64 + c] = f2bf(acc[j]);
    __syncthreads();
#pragma unroll
    for (int p = 0; p < 2; p++) {
        int idx = tid + p * 256;
        int row = idx >> 3, cg = idx & 7;
        ushort8 v = *(const ushort8*)(&ot[row * 64 + cg * 8]);
        char* dst = (char*)outp + ((size_t)(b * SEQ_LEN + l0 + row) * 2048) + dt * 256 + cg * 16;
        *(ushort8*)dst = v;
    }
}

// ---------------- K2: per-phase GEMM on MFMA, IN-PLACE on d_out -------------
// grid (8 d-tiles, 32 phases, 32 b); block 256 = 4 waves.
// Reads bf16 X slices (128 rows x 128 B, each one full cache line) that this
// block alone later overwrites with fp32 Y (reads precede writes via barrier).
// A-fragments come straight from bf16 W in d_ws (L2-resident) — no W LDS.
#define XS 136   // ushort row stride: 272 B, 16 B-aligned rows
__global__ __launch_bounds__(256, 4) void k_gemm(const unsigned short* __restrict__ wb,
                                                 float* __restrict__ outp) {
    __shared__ unsigned short xl[64 * XS];   // 17408 B, xl[d][ii] with XOR-block swizzle

    const int tid = threadIdx.x;
    const int dt = blockIdx.x, ph = blockIdx.y, b = blockIdx.z;

    const char* xbase = (const char*)outp
                      + ((size_t)(b * SEQ_LEN + ph) * D_MODEL + dt * 64) * 4;
    // stage X^T: i-pairs packed to u32, 16-B block index XORed with (d>>3)
    // (write and read use the same involution -> conflict-free both sides)
#pragma unroll
    for (int p = 0; p < 2; p++) {
        int idx = tid + p * 256;
        int pr = idx >> 3;            // i-pair 0..63
        int cg = idx & 7;             // d-chunk 0..7 (8 ushorts each)
        const char* src = xbase + (size_t)(2 * pr) * (32 * 2048) + cg * 16;
        ushort8 r0 = *(const ushort8*)(src);
        ushort8 r1 = *(const ushort8*)(src + 32 * 2048);
        int B = pr >> 2;              // ii block (ii = 2*pr)
        int wof = (2 * pr) & 7;
#pragma unroll
        for (int dd = 0; dd < 8; dd++) {
            int d = cg * 8 + dd;
            unsigned int pk = (unsigned int)r0[dd] | ((unsigned int)r1[dd] << 16);
            *(unsigned int*)(&xl[d * XS + ((B ^ cg) << 3) + wof]) = pk;
        }
    }
    __syncthreads();

    const int lane = tid & 63, wid = tid >> 6, q = lane >> 4, r16 = lane & 15;

    float4v acc[2][4] = {};
#pragma unroll
    for (int kb = 0; kb < 128; kb += 32) {
        short8 a[2];
#pragma unroll
        for (int mt = 0; mt < 2; mt++) {
            int row = wid * 32 + mt * 16 + r16;                 // m
            a[mt] = *(const short8*)(wb + row * 128 + kb + q * 8);
        }
#pragma unroll
        for (int dtl = 0; dtl < 4; dtl++) {
            int d = dtl * 16 + r16;
            int Bb = ((kb >> 3) + q) ^ (d >> 3);
            short8 bfrag = *(const short8*)(&xl[d * XS + (Bb << 3)]);
#pragma unroll
            for (int mt = 0; mt < 2; mt++)
                acc[mt][dtl] = __builtin_amdgcn_mfma_f32_16x16x32_bf16(
                    a[mt], bfrag, acc[mt][dtl], 0, 0, 0);
        }
    }

    // --- epilogue: D col = lane&15 -> d, row = quad*4 + reg -> m ---
    float* ob = outp + ((size_t)b * SEQ_LEN) * D_MODEL;
#pragma unroll
    for (int mt = 0; mt < 2; mt++) {
        int mbase = wid * 32 + mt * 16 + q * 4;
#pragma unroll
        for (int r = 0; r < 4; r++) {
            int m = mbase + r;
            int hidx = m * 32 + ph;
#pragma unroll
            for (int dtl = 0; dtl < 4; dtl++) {
                int d = dt * 64 + dtl * 16 + r16;
                ob[(size_t)hidx * D_MODEL + d] = acc[mt][dtl][r];
            }
        }
    }
}

extern "C" void kernel_launch(void* const* d_in, const int* in_sizes, int n_in,
                              void* d_out, int out_size, void* d_ws, size_t ws_size,
                              hipStream_t stream) {
    const float* h  = (const float*)d_in[0];
    const float* cw = (const float*)d_in[1];   // [512][1][33]
    const float* bw = (const float*)d_in[2];   // [128][128]
    float* out = (float*)d_out;

    unsigned short* wb = (unsigned short*)d_ws;            // 32 KB bf16 W
    float* wt = (float*)((char*)d_ws + 32768);             // 66 KB wt[33][512]

    k_prep<<<dim3(66), 256, 0, stream>>>(bw, cw, wb, wt);
    k_conv<<<dim3(64, 8, 32), 256, 0, stream>>>(h, wt, out);
    k_gemm<<<dim3(8, 32, 32), 256, 0, stream>>>(wb, out);
}

// Round 2
// 913.168 us; speedup vs baseline: 1.0355x; 1.0355x over previous
//
#include <hip/hip_runtime.h>

#define SEQ_LEN 4096
#define D_MODEL 512
#define KSZ 33

typedef __attribute__((ext_vector_type(4))) float float4v;
typedef __attribute__((ext_vector_type(8))) short short8;

static __device__ __forceinline__ unsigned short f2bf(float f) {
    unsigned int u = __float_as_uint(f);
    u += 0x7fffu + ((u >> 16) & 1u);   // round-to-nearest-even
    return (unsigned short)(u >> 16);
}

// ---------------- K0: prep — backbone W fp32->bf16 (16384 elems into d_ws),
// conv weights transposed to wt[k][d] fp32 (33*512) so K1 reads them coalesced.
__global__ __launch_bounds__(256) void k_prep(const float* __restrict__ bw,
                                              const float* __restrict__ cw,
                                              unsigned short* __restrict__ wb,
                                              float* __restrict__ wt) {
    int i = blockIdx.x * 256 + threadIdx.x;
    if (i < 128 * 128) wb[i] = f2bf(bw[i]);
    if (i < KSZ * D_MODEL) {
        int k = i >> 9, d = i & 511;           // i = k*512 + d
        wt[i] = cw[(size_t)d * KSZ + k];
    }
}

// ---------------- K1: residual depthwise conv, fp32 -> fp32 (into d_out) ----
// grid (64 l-tiles, 8 d-tiles, 32 b); block 256 (4 waves x 16 l-rows each).
// float4 staging (16 B/lane), rolling 16-register window (48 LDS reads/thread,
// structurally impossible for the compiler to sink), weights from L1-resident
// transposed table. Stores: 64 lanes x 4 B = full 256-B slots (round-0-proven
// zero write amplification: WRITE_SIZE == 262144 KB exactly).
__global__ __launch_bounds__(256, 6) void k_conv(const float* __restrict__ h,
                                                 const float* __restrict__ wt,
                                                 float* __restrict__ outp) {
    __shared__ float tile[96][64];   // 24576 B -> 6 blocks/CU

    const int lt = blockIdx.x, dt = blockIdx.y, b = blockIdx.z;
    const int tid = threadIdx.x;
    const int l0 = lt * 64;

    // --- stage h tile with float4 (16 B/lane) ---
    const float* hb = h + ((size_t)b * SEQ_LEN) * D_MODEL + dt * 64;
    {
        const int cg = (tid & 15) * 4;
#pragma unroll
        for (int rr = 0; rr < 6; rr++) {
            int r = (tid >> 4) + rr * 16;
            int l = l0 - 16 + r;
            float4v v = {0.f, 0.f, 0.f, 0.f};
            if (l >= 0 && l < SEQ_LEN) v = *(const float4v*)(hb + (size_t)l * D_MODEL + cg);
            *(float4v*)(&tile[r][cg]) = v;
        }
    }
    __syncthreads();

    const int c = tid & 63;
    const int lsub = (tid >> 6) * 16;
    const float* wcol = wt + dt * 64 + c;      // wt[k][dt*64+c], L1-resident

    float buf[16];                              // rolling window
#pragma unroll
    for (int j = 0; j < 16; j++) buf[j] = tile[lsub + j][c];
    float acc[16] = {};
#pragma unroll
    for (int k = 0; k < KSZ; k++) {
        // residual h[l] == window value at k==16 -> fold into weight (+1)
        float wk = wcol[(size_t)k * D_MODEL] + ((k == 16) ? 1.0f : 0.0f);
#pragma unroll
        for (int j = 0; j < 16; j++) acc[j] += wk * buf[j];
        if (k < 32) {
#pragma unroll
            for (int j = 0; j < 15; j++) buf[j] = buf[j + 1];
            buf[15] = tile[lsub + k + 16][c];
        }
    }

    // --- direct fp32 stores: each instruction = 64 lanes x 4 B contiguous ---
    float* ob = outp + ((size_t)(b * SEQ_LEN + l0 + lsub)) * D_MODEL + dt * 64 + c;
#pragma unroll
    for (int j = 0; j < 16; j++) ob[(size_t)j * D_MODEL] = acc[j];
}

// ---------------- K2: per-phase GEMM on MFMA, IN-PLACE on d_out -------------
// grid (8 d-tiles, 32 phases, 32 b); block 256 = 4 waves.
// Block (dt,ph,b) reads fp32 X = out[(b*4096 + i*32+ph)*512 + dt*64 + d]
// (i,d in [0,128)x[0,64)) and writes Y to the exact same element set
// (hidx = m*32+ph): unique owner; reads precede writes via __syncthreads.
// A-fragments straight from bf16 W in d_ws (L1-resident) — no W LDS.
#define XS 136   // ushort row stride
__global__ __launch_bounds__(256, 4) void k_gemm(const unsigned short* __restrict__ wb,
                                                 float* __restrict__ outp) {
    __shared__ unsigned short xl[64 * XS];   // 17408 B, xl[d][i] XOR-block-swizzled

    const int tid = threadIdx.x;
    const int dt = blockIdx.x, ph = blockIdx.y, b = blockIdx.z;

    // --- stage X^T: fp32 -> bf16, i-pairs packed to u32, swizzled ---
    {
        const int dgrp = (tid & 15) * 4;      // d = dgrp..dgrp+3
        const int ipair = tid >> 4;
        const float* xb = outp + ((size_t)(b * SEQ_LEN) + ph) * D_MODEL
                        + dt * 64 + dgrp;
#pragma unroll
        for (int pass = 0; pass < 4; pass++) {
            int i0 = pass * 32 + ipair * 2;
            float4v v0 = *(const float4v*)(xb + (size_t)i0 * 32 * D_MODEL);
            float4v v1 = *(const float4v*)(xb + (size_t)(i0 + 1) * 32 * D_MODEL);
#pragma unroll
            for (int dd = 0; dd < 4; dd++) {
                int d = dgrp + dd;
                unsigned int pk = (unsigned int)f2bf(v0[dd])
                                | ((unsigned int)f2bf(v1[dd]) << 16);
                int off = d * XS + ((((i0 >> 3) ^ (d >> 3))) << 3) + (i0 & 7);
                *(unsigned int*)(&xl[off]) = pk;
            }
        }
    }
    __syncthreads();

    const int lane = tid & 63, wid = tid >> 6, q = lane >> 4, r16 = lane & 15;

    float4v acc[2][4] = {};
#pragma unroll
    for (int kb = 0; kb < 128; kb += 32) {
        short8 a[2];
#pragma unroll
        for (int mt = 0; mt < 2; mt++) {
            int row = wid * 32 + mt * 16 + r16;                 // m
            a[mt] = *(const short8*)(wb + row * 128 + kb + q * 8);
        }
#pragma unroll
        for (int dtl = 0; dtl < 4; dtl++) {
            int d = dtl * 16 + r16;
            int Bb = ((kb >> 3) + q) ^ (d >> 3);
            short8 bfrag = *(const short8*)(&xl[d * XS + (Bb << 3)]);
#pragma unroll
            for (int mt = 0; mt < 2; mt++)
                acc[mt][dtl] = __builtin_amdgcn_mfma_f32_16x16x32_bf16(
                    a[mt], bfrag, acc[mt][dtl], 0, 0, 0);
        }
    }

    // --- epilogue: D col = lane&15 -> d, row = quad*4 + reg -> m ---
    float* ob = outp + ((size_t)b * SEQ_LEN) * D_MODEL;
#pragma unroll
    for (int mt = 0; mt < 2; mt++) {
        int mbase = wid * 32 + mt * 16 + q * 4;
#pragma unroll
        for (int r = 0; r < 4; r++) {
            int m = mbase + r;
            int hidx = m * 32 + ph;
#pragma unroll
            for (int dtl = 0; dtl < 4; dtl++) {
                int d = dt * 64 + dtl * 16 + r16;
                ob[(size_t)hidx * D_MODEL + d] = acc[mt][dtl][r];
            }
        }
    }
}

extern "C" void kernel_launch(void* const* d_in, const int* in_sizes, int n_in,
                              void* d_out, int out_size, void* d_ws, size_t ws_size,
                              hipStream_t stream) {
    const float* h  = (const float*)d_in[0];
    const float* cw = (const float*)d_in[1];   // [512][1][33]
    const float* bw = (const float*)d_in[2];   // [128][128]
    float* out = (float*)d_out;

    unsigned short* wb = (unsigned short*)d_ws;            // 32 KB bf16 W
    float* wt = (float*)((char*)d_ws + 32768);             // 66 KB wt[33][512]

    k_prep<<<dim3(66), 256, 0, stream>>>(bw, cw, wb, wt);
    k_conv<<<dim3(64, 8, 32), 256, 0, stream>>>(h, wt, out);
    k_gemm<<<dim3(8, 32, 32), 256, 0, stream>>>(wb, out);
}

// Round 4
// 740.890 us; speedup vs baseline: 1.2762x; 1.2325x over previous
//
#include <hip/hip_runtime.h>

#define SEQ_LEN 4096
#define D_MODEL 512
#define KSZ 33

typedef __attribute__((ext_vector_type(4))) float float4v;
typedef __attribute__((ext_vector_type(8))) short short8;

static __device__ __forceinline__ unsigned short f2bf(float f) {
    unsigned int u = __float_as_uint(f);
    u += 0x7fffu + ((u >> 16) & 1u);   // round-to-nearest-even
    return (unsigned short)(u >> 16);
}

// ---------------- K0: prep — backbone W fp32->bf16 into d_ws ---------------
__global__ __launch_bounds__(256) void k_prep(const float* __restrict__ bw,
                                              unsigned short* __restrict__ wb) {
    int i = blockIdx.x * 256 + threadIdx.x;
    if (i < 128 * 128) wb[i] = f2bf(bw[i]);
}

// ---------------- K1: residual depthwise conv, fp32 -> fp32 (into d_out) ----
// Memory pattern VERBATIM from the round-0 kernel (proven clean: WRITE_SIZE
// exactly 262144 KB, FETCH 197 MB, 0 bank conflicts). Only the inner loop
// changes: modular rolling window buf[(k+j)&15] with compile-time indices ->
// 81 LDS reads/thread instead of the compiler-sunk ~530 (round-0 was LDS-
// issue-bound: 530 reads * 16 waves/CU * 5.8 cyc * 16 batches ~= 327 us).
__global__ __launch_bounds__(256) void k_conv(const float* __restrict__ h,
                                              const float* __restrict__ cw,
                                              float* __restrict__ hagg) {
    __shared__ float tile[96][64];   // rows l0-16 .. l0+79
    __shared__ float wsh[64][33];

    const int lt = blockIdx.x, dt = blockIdx.y, b = blockIdx.z;
    const int tid = threadIdx.x;
    const int c = tid & 63;          // local d
    const int l0 = lt * 64;

    const float* hb = h + ((size_t)b * SEQ_LEN) * D_MODEL + dt * 64;
    for (int r = (tid >> 6); r < 96; r += 4) {
        int l = l0 - 16 + r;
        float v = 0.f;
        if (l >= 0 && l < SEQ_LEN) v = hb[(size_t)l * D_MODEL + c];
        tile[r][c] = v;
    }
    for (int idx = tid; idx < 64 * KSZ; idx += 256) {
        int dd = idx / KSZ, k = idx - dd * KSZ;
        wsh[dd][k] = cw[(size_t)(dt * 64 + dd) * KSZ + k];
    }
    __syncthreads();

    const int lsub = (tid >> 6) * 16;

    float buf[16];                   // rolling window, all indices static
#pragma unroll
    for (int j = 0; j < 16; j++) buf[j] = tile[lsub + j][c];

    float acc[16] = {};
#pragma unroll
    for (int k = 0; k < KSZ; k++) {
        // residual h[l] == window element at k==16 -> fold into weight (+1)
        float wk = wsh[c][k] + ((k == 16) ? 1.0f : 0.0f);
#pragma unroll
        for (int j = 0; j < 16; j++) acc[j] += wk * buf[(k + j) & 15];
        if (k < 32) buf[k & 15] = tile[lsub + k + 16][c];
    }

    float* ob = hagg + ((size_t)b * SEQ_LEN + l0 + lsub) * D_MODEL + dt * 64 + c;
#pragma unroll
    for (int j = 0; j < 16; j++) ob[(size_t)j * D_MODEL] = acc[j];
}

// ---------------- K2: per-phase GEMM on MFMA, IN-PLACE on d_out -------------
// grid (2 d-halves, 32 phases, 32 b); block 256 = 4 waves; 2048 blocks.
// Block (dh,ph,b) stages X = out[rows i*32+ph][cols dh*256..+256) — each
// global read/write is a FULL 1-KB contiguous row (vs round-0's 256-B slivers
// split across 8 dt-blocks on different XCDs). Writes Y to the same element
// set (unique owner; reads precede writes via __syncthreads).
// W read as bf16 a-frags straight from d_ws: each element once per block,
// L1-resident. 512 MFMA/block = 128/wave.
#define XSTR 136   // u16 row stride (272 B): 16-B aligned rows
__global__ __launch_bounds__(256, 2) void k_gemm(const unsigned short* __restrict__ wb,
                                                 float* __restrict__ outp) {
    __shared__ unsigned short xl[256 * XSTR];   // 69632 B -> 2 blocks/CU

    const int tid = threadIdx.x;
    const int dh = blockIdx.x, ph = blockIdx.y, b = blockIdx.z;
    const int lane = tid & 63, w = tid >> 6;

    // --- stage X^T: fp32 -> bf16, i-pairs packed to u32, XOR-block swizzle ---
    // wave w, pass p: i-pair ip = p*4+w; lane covers d = lane*4..+3.
    {
        const float* xrow0 = outp + ((size_t)(b * SEQ_LEN) + ph) * D_MODEL
                           + dh * 256 + lane * 4;
#pragma unroll
        for (int p = 0; p < 16; p++) {
            int ip = p * 4 + w;                  // 0..63
            int i0 = ip * 2;
            const float* src = xrow0 + (size_t)i0 * 32 * D_MODEL;
            float4v v0 = *(const float4v*)(src);
            float4v v1 = *(const float4v*)(src + 32 * D_MODEL);
            int ib = i0 >> 3;                    // 8-i block index 0..15
            int wof = i0 & 7;                    // even
#pragma unroll
            for (int dd = 0; dd < 4; dd++) {
                int d = lane * 4 + dd;
                unsigned int pk = (unsigned int)f2bf(v0[dd])
                                | ((unsigned int)f2bf(v1[dd]) << 16);
                int off = d * XSTR + (((ib ^ (d >> 3)) & 15) << 3) + wof;
                *(unsigned int*)(&xl[off]) = pk;
            }
        }
    }
    __syncthreads();

    const int q = lane >> 4, r16 = lane & 15;

    // wave owns m in [w*32, w*32+32) x all 256 d-cols of this half
    float4v acc[2][16] = {};
#pragma unroll
    for (int kb = 0; kb < 128; kb += 32) {
        short8 a[2];
#pragma unroll
        for (int mt = 0; mt < 2; mt++) {
            int row = w * 32 + mt * 16 + r16;                    // m
            a[mt] = *(const short8*)(wb + row * 128 + kb + q * 8);
        }
#pragma unroll
        for (int dtl = 0; dtl < 16; dtl++) {
            int d = dtl * 16 + r16;
            int ib = (kb >> 3) + q;
            short8 bfrag = *(const short8*)(&xl[d * XSTR + (((ib ^ (d >> 3)) & 15) << 3)]);
#pragma unroll
            for (int mt = 0; mt < 2; mt++)
                acc[mt][dtl] = __builtin_amdgcn_mfma_f32_16x16x32_bf16(
                    a[mt], bfrag, acc[mt][dtl], 0, 0, 0);
        }
    }

    // --- epilogue: D col = lane&15 -> d, row = quad*4 + reg -> m ---
    float* ob = outp + ((size_t)b * SEQ_LEN) * D_MODEL;
#pragma unroll
    for (int mt = 0; mt < 2; mt++) {
        int mbase = w * 32 + mt * 16 + q * 4;
#pragma unroll
        for (int r = 0; r < 4; r++) {
            int m = mbase + r;
            int hidx = m * 32 + ph;
#pragma unroll
            for (int dtl = 0; dtl < 16; dtl++) {
                int d = dh * 256 + dtl * 16 + r16;
                ob[(size_t)hidx * D_MODEL + d] = acc[mt][dtl][r];
            }
        }
    }
}

extern "C" void kernel_launch(void* const* d_in, const int* in_sizes, int n_in,
                              void* d_out, int out_size, void* d_ws, size_t ws_size,
                              hipStream_t stream) {
    const float* h  = (const float*)d_in[0];
    const float* cw = (const float*)d_in[1];   // [512][1][33]
    const float* bw = (const float*)d_in[2];   // [128][128]
    float* out = (float*)d_out;

    unsigned short* wb = (unsigned short*)d_ws;    // 32 KB bf16 W

    k_prep<<<dim3(64), 256, 0, stream>>>(bw, wb);
    k_conv<<<dim3(64, 8, 32), 256, 0, stream>>>(h, cw, out);
    k_gemm<<<dim3(2, 32, 32), 256, 0, stream>>>(wb, out);
}

// Round 5
// 693.661 us; speedup vs baseline: 1.3631x; 1.0681x over previous
//
#include <hip/hip_runtime.h>

#define SEQ_LEN 4096
#define D_MODEL 512
#define KSZ 33

typedef __attribute__((ext_vector_type(4))) float float4v;
typedef __attribute__((ext_vector_type(8))) short short8;

static __device__ __forceinline__ unsigned short f2bf(float f) {
    unsigned int u = __float_as_uint(f);
    u += 0x7fffu + ((u >> 16) & 1u);   // round-to-nearest-even
    return (unsigned short)(u >> 16);
}

// ---------------- K0: prep — backbone W fp32->bf16 into d_ws; conv weights
// transposed to wt[k][d] (33*512 fp32) so K1 reads them coalesced/L1-resident.
__global__ __launch_bounds__(256) void k_prep(const float* __restrict__ bw,
                                              const float* __restrict__ cw,
                                              unsigned short* __restrict__ wb,
                                              float* __restrict__ wt) {
    int i = blockIdx.x * 256 + threadIdx.x;
    if (i < 128 * 128) wb[i] = f2bf(bw[i]);
    if (i < KSZ * D_MODEL) {
        int k = i >> 9, d = i & 511;           // i = k*512 + d
        wt[i] = cw[(size_t)d * KSZ + k];
    }
}

// ---------------- K1: residual depthwise conv, fp32 -> fp32 (into d_out) ----
// Memory pattern verbatim round-0 (proven: WRITE exactly 262144 KB, FETCH
// 197 MB, 0 conflicts). Round-4 lesson: an unrolled rolling window is SSA-
// forwarded back into tile[] loads and re-sunk (~530 ds_read/thread ->
// 327 us). Fix: asm-pin each window value so the compiler must keep it in a
// VGPR -> 48 ds_read/thread. Weights from global wt (coalesced, L1-hit),
// freeing the wsh LDS and its reads.
__global__ __launch_bounds__(256) void k_conv(const float* __restrict__ h,
                                              const float* __restrict__ wt,
                                              float* __restrict__ hagg) {
    __shared__ float tile[96][64];   // rows l0-16 .. l0+79 (24576 B)

    const int lt = blockIdx.x, dt = blockIdx.y, b = blockIdx.z;
    const int tid = threadIdx.x;
    const int c = tid & 63;          // local d
    const int l0 = lt * 64;

    const float* hb = h + ((size_t)b * SEQ_LEN) * D_MODEL + dt * 64;
    for (int r = (tid >> 6); r < 96; r += 4) {
        int l = l0 - 16 + r;
        float v = 0.f;
        if (l >= 0 && l < SEQ_LEN) v = hb[(size_t)l * D_MODEL + c];
        tile[r][c] = v;
    }
    __syncthreads();

    const int lsub = (tid >> 6) * 16;
    const float* wcol = wt + dt * 64 + c;      // wt[k][dt*64+c]

    float buf[16];                   // rolling window, pinned into VGPRs
#pragma unroll
    for (int j = 0; j < 16; j++) {
        buf[j] = tile[lsub + j][c];
        asm volatile("" : "+v"(buf[j]));       // opaque: no remat from LDS
    }

    float acc[16] = {};
#pragma unroll
    for (int k = 0; k < KSZ; k++) {
        // residual h[l] == window element at k==16 -> fold into weight (+1)
        float wk = wcol[(size_t)k * D_MODEL] + ((k == 16) ? 1.0f : 0.0f);
#pragma unroll
        for (int j = 0; j < 16; j++) acc[j] += wk * buf[(k + j) & 15];
        if (k < 32) {
            buf[k & 15] = tile[lsub + k + 16][c];
            asm volatile("" : "+v"(buf[k & 15]));
        }
    }

    float* ob = hagg + ((size_t)b * SEQ_LEN + l0 + lsub) * D_MODEL + dt * 64 + c;
#pragma unroll
    for (int j = 0; j < 16; j++) ob[(size_t)j * D_MODEL] = acc[j];
}

// ---------------- K2: per-phase GEMM on MFMA, IN-PLACE on d_out -------------
// grid (2 d-halves, 32 phases, 32 b); block 512 = 8 waves; 2 blocks/CU ->
// 16 waves/CU (2x round-4's occupancy, which was 94% latency-stalled).
// Staging issues 8 independent 1-KB row loads in flight before converting.
// Epilogue: LDS-transpose (reusing the X buffer) -> full 1-KB contiguous
// row stores instead of 128 scattered dwords/thread.
// Unique owner in place: block (dh,ph,b) reads rows i*32+ph and writes rows
// m*32+ph over the same d-columns; all global reads precede first store.
#define XSTR 136   // u16 row stride (272 B)
__global__ __launch_bounds__(512, 4) void k_gemm(const unsigned short* __restrict__ wb,
                                                 float* __restrict__ outp) {
    __shared__ __attribute__((aligned(16))) unsigned short xl[256 * XSTR]; // 69632 B

    const int tid = threadIdx.x;
    const int dh = blockIdx.x, ph = blockIdx.y, b = blockIdx.z;
    const int lane = tid & 63, w = tid >> 6;   // w in 0..7

    // --- stage X^T: fp32 -> bf16, i-pairs packed to u32, XOR-block swizzle ---
    {
        const float* xrow0 = outp + ((size_t)(b * SEQ_LEN) + ph) * D_MODEL
                           + dh * 256 + lane * 4;
#pragma unroll
        for (int c2 = 0; c2 < 2; c2++) {
            float4v va[4], vb[4];
#pragma unroll
            for (int pp = 0; pp < 4; pp++) {           // 8 loads in flight
                int ip = (c2 * 4 + pp) * 8 + w;        // i-pair 0..63
                const float* src = xrow0 + (size_t)(ip * 2) * 32 * D_MODEL;
                va[pp] = *(const float4v*)(src);
                vb[pp] = *(const float4v*)(src + 32 * D_MODEL);
            }
#pragma unroll
            for (int pp = 0; pp < 4; pp++) {
                int i0 = ((c2 * 4 + pp) * 8 + w) * 2;
                int ib = i0 >> 3, wof = i0 & 7;
#pragma unroll
                for (int dd = 0; dd < 4; dd++) {
                    int d = lane * 4 + dd;
                    unsigned int pk = (unsigned int)f2bf(va[pp][dd])
                                    | ((unsigned int)f2bf(vb[pp][dd]) << 16);
                    int off = d * XSTR + (((ib ^ (d >> 3)) & 15) << 3) + wof;
                    *(unsigned int*)(&xl[off]) = pk;
                }
            }
        }
    }
    __syncthreads();

    const int q = lane >> 4, r16 = lane & 15;

    // wave owns m in [w*16, w*16+16) x all 256 d-cols of this half
    float4v acc[16] = {};
#pragma unroll
    for (int kb = 0; kb < 128; kb += 32) {
        short8 a = *(const short8*)(wb + (w * 16 + r16) * 128 + kb + q * 8);
#pragma unroll
        for (int dtl = 0; dtl < 16; dtl++) {
            int d = dtl * 16 + r16;
            int ib = (kb >> 3) + q;
            short8 bfrag = *(const short8*)(&xl[d * XSTR + (((ib ^ (d >> 3)) & 15) << 3)]);
            acc[dtl] = __builtin_amdgcn_mfma_f32_16x16x32_bf16(a, bfrag, acc[dtl], 0, 0, 0);
        }
    }
    __syncthreads();   // all xl reads done; buffer reusable for Y staging

    // --- epilogue: two 64-row halves through LDS -> 1-KB contiguous stores ---
    float* yt = (float*)xl;            // [64][260] fp32 = 66560 B (stride 260:
                                       // 2-way-max bank pattern, 16-B aligned)
    float* ob = outp + ((size_t)b * SEQ_LEN) * D_MODEL;
#pragma unroll
    for (int half = 0; half < 2; half++) {
        if ((w >> 2) == half) {
            int mloc = (w & 3) * 16 + q * 4;
#pragma unroll
            for (int dtl = 0; dtl < 16; dtl++)
#pragma unroll
                for (int r = 0; r < 4; r++)
                    yt[(mloc + r) * 260 + dtl * 16 + r16] = acc[dtl][r];
        }
        __syncthreads();
        // each wave streams one full row per iteration: 64 lanes x 16 B = 1 KB
#pragma unroll
        for (int it = 0; it < 8; it++) {
            int row = it * 8 + w;                      // 0..63
            float4v v = *(const float4v*)(&yt[row * 260 + lane * 4]);
            int m = half * 64 + row;
            *(float4v*)(ob + ((size_t)(m * 32 + ph)) * D_MODEL + dh * 256 + lane * 4) = v;
        }
        __syncthreads();
    }
}

extern "C" void kernel_launch(void* const* d_in, const int* in_sizes, int n_in,
                              void* d_out, int out_size, void* d_ws, size_t ws_size,
                              hipStream_t stream) {
    const float* h  = (const float*)d_in[0];
    const float* cw = (const float*)d_in[1];   // [512][1][33]
    const float* bw = (const float*)d_in[2];   // [128][128]
    float* out = (float*)d_out;

    unsigned short* wb = (unsigned short*)d_ws;            // 32 KB bf16 W
    float* wt = (float*)((char*)d_ws + 32768);             // 66 KB wt[33][512]

    k_prep<<<dim3(66), 256, 0, stream>>>(bw, cw, wb, wt);
    k_conv<<<dim3(64, 8, 32), 256, 0, stream>>>(h, wt, out);
    k_gemm<<<dim3(2, 32, 32), 512, 0, stream>>>(wb, out);
}